// Round 1
// 130.341 us; speedup vs baseline: 1.1545x; 1.1545x over previous
//
#include <hip/hip_runtime.h>
#include <math.h>

#define BSZ 16
#define NQ 300
#define NT 50
#define K3 51
#define NPRED (BSZ*NQ)     // 4800
#define NTGT  (BSZ*NT)     // 800
#define NC    (NPRED*NTGT) // 3,840,000
#define TSTRIDE 301        // lap tile row stride (floats), odd -> conflict-free
#define SMEMF 15232        // floats: 50*301 tile + rowmin scratch (60.9 KB, 2 blk/CU)

// ---------------- DPP wave-min helper (wave64, all lanes active) ----------------
template<int CTRL, int RMASK>
__device__ __forceinline__ double dpp_minstep_f64(double x) {
    long long bb = __double_as_longlong(x);
    int lo = (int)(bb & 0xFFFFFFFFll);
    int hi = (int)(bb >> 32);
    int mlo = __builtin_amdgcn_update_dpp(lo, lo, CTRL, RMASK, 0xF, false);
    int mhi = __builtin_amdgcn_update_dpp(hi, hi, CTRL, RMASK, 0xF, false);
    double other = __longlong_as_double(((long long)mhi << 32) | (long long)(unsigned)mlo);
    return fmin(x, other);
}
__device__ __forceinline__ double wave_min_f64(double x) {
    x = dpp_minstep_f64<0xB1, 0xF>(x);
    x = dpp_minstep_f64<0x4E, 0xF>(x);
    x = dpp_minstep_f64<0x141, 0xF>(x);
    x = dpp_minstep_f64<0x140, 0xF>(x);
    x = dpp_minstep_f64<0x142, 0xA>(x);   // lanes 16-31,48-63 <- lane 15/47
    x = dpp_minstep_f64<0x143, 0xC>(x);   // lanes 32-63 <- lane 31; lane 63 = global min
    long long bb = __double_as_longlong(x);
    int lo = __builtin_amdgcn_readlane((int)(bb & 0xFFFFFFFFll), 63);
    int hi = __builtin_amdgcn_readlane((int)(bb >> 32), 63);
    return __longlong_as_double(((long long)hi << 32) | (long long)(unsigned)lo);
}
__device__ __forceinline__ double readlane_f64(double x, int lane) {
    long long bb = __double_as_longlong(x);
    int lo = __builtin_amdgcn_readlane((int)(bb & 0xFFFFFFFFll), lane);
    int hi = __builtin_amdgcn_readlane((int)(bb >> 32), lane);
    return __longlong_as_double(((long long)hi << 32) | (long long)(unsigned)lo);
}

// Identical formula/op-order used by BOTH paths -> bitwise-identical cost values.
__device__ __forceinline__ float giou_cost(
    float plt0, float plt1, float plt2, float prb0, float prb1, float prb2, float pvol,
    float tlt0, float tlt1, float tlt2, float trb0, float trb1, float trb2, float tvol)
{
    float inter = fmaxf(fminf(prb0,trb0) - fmaxf(plt0,tlt0), 0.f);
    inter *= fmaxf(fminf(prb1,trb1) - fmaxf(plt1,tlt1), 0.f);
    inter *= fmaxf(fminf(prb2,trb2) - fmaxf(plt2,tlt2), 0.f);
    float evol = fmaxf(fmaxf(prb0,trb0) - fminf(plt0,tlt0), 0.f);
    evol *= fmaxf(fmaxf(prb1,trb1) - fminf(plt1,tlt1), 0.f);
    evol *= fmaxf(fmaxf(prb2,trb2) - fminf(plt2,tlt2), 0.f);
    float uni = pvol + tvol - inter;
    return inter/uni - (evol - uni)/evol;
}

__global__ __launch_bounds__(1024) void fused_kernel(
    const float* __restrict__ pred_kp, const float* __restrict__ pred_boxes,
    const float* __restrict__ tgt_boxes, const float* __restrict__ tgt_kp,
    float* __restrict__ C, float* __restrict__ out_idx)
{
    __shared__ __align__(16) float smem[SMEMF];
    const int bid = blockIdx.x;
    const int tid = threadIdx.x;

    if (bid >= BSZ) {
        // ================= cost-matrix path: 64 preds x 80 tgts per block =================
        const int cb = bid - BSZ;
        const int pb = cb % 75, tb = cb / 75;
        const int p0 = pb * 64, t0 = tb * 80;
        float* s_dk   = smem;            // 80 x 56 (padded, 16B-aligned rows)
        float* s_tbox = smem + 4480;     // 80 x 12: lt0-2, rb0-2, vol, pad, pad, s0-2
        float* s_pk   = smem + 5440;     // 64 x 51

        if (tid < 80) {
            const float* tb6 = tgt_boxes + (size_t)(t0 + tid) * 6;
            float c0=tb6[0], c1=tb6[1], c2=tb6[2], s0=tb6[3], s1=tb6[4], s2=tb6[5];
            float l0=c0-0.5f*s0, l1=c1-0.5f*s1, l2=c2-0.5f*s2;
            float r0=c0+0.5f*s0, r1=c1+0.5f*s1, r2=c2+0.5f*s2;
            float* tw = s_tbox + tid*12;
            tw[0]=l0; tw[1]=l1; tw[2]=l2; tw[3]=r0; tw[4]=r1; tw[5]=r2;
            tw[6]=(r0-l0)*(r1-l1)*(r2-l2);
            tw[9]=s0; tw[10]=s1; tw[11]=s2;
        }
        __syncthreads();
        for (int e = tid; e < 80*K3; e += 1024) {
            int t = e / K3; int c = e - t*K3; int d = c % 3;
            float kp = tgt_kp[(size_t)t0*K3 + e];
            s_dk[t*56 + c] = (kp - s_tbox[t*12 + d]) / s_tbox[t*12 + 9 + d];
        }
        for (int e = tid; e < 64*K3; e += 1024)
            s_pk[e] = pred_kp[(size_t)p0*K3 + e];
        __syncthreads();

        const int pl = tid & 63, g = tid >> 6;
        float a[K3];
        #pragma unroll
        for (int c = 0; c < K3; ++c) a[c] = s_pk[pl*K3 + c];
        const int p = p0 + pl;
        const float* pb6 = pred_boxes + (size_t)p * 6;
        float pc0=pb6[0],pc1=pb6[1],pc2=pb6[2],ps0=pb6[3],ps1=pb6[4],ps2=pb6[5];
        float plt0=pc0-0.5f*ps0, plt1=pc1-0.5f*ps1, plt2=pc2-0.5f*ps2;
        float prb0=pc0+0.5f*ps0, prb1=pc1+0.5f*ps1, prb2=pc2+0.5f*ps2;
        float pvol=(prb0-plt0)*(prb1-plt1)*(prb2-plt2);

        #pragma unroll
        for (int k = 0; k < 5; ++k) {
            int tl = g*5 + k;                       // wave-uniform -> broadcast LDS reads
            const float* bbp = s_dk + tl*56;
            float sum = 0.f;
            #pragma unroll
            for (int c4 = 0; c4 < 12; ++c4) {       // ascending c, serial adds (order fixed)
                float4 q = *(const float4*)(bbp + 4*c4);
                sum += fabsf(a[4*c4+0] - q.x);
                sum += fabsf(a[4*c4+1] - q.y);
                sum += fabsf(a[4*c4+2] - q.z);
                sum += fabsf(a[4*c4+3] - q.w);
            }
            sum += fabsf(a[48] - bbp[48]);
            sum += fabsf(a[49] - bbp[49]);
            sum += fabsf(a[50] - bbp[50]);
            const float* tw = s_tbox + tl*12;
            float g_ = giou_cost(plt0,plt1,plt2,prb0,prb1,prb2,pvol,
                                 tw[0],tw[1],tw[2],tw[3],tw[4],tw[5],tw[6]);
            C[(size_t)p*NTGT + (t0+tl)] = sum - g_;
        }
        return;
    }

    // ================= LAP path: one block per batch =================
    const int b = bid;
    const int ln = tid & 63, w = tid >> 6;
    const int bq0 = b*NQ, bt0 = b*NT;
    float* tile = smem;                 // becomes [50][301] cost tile

    // stage tgt_kp slice into (future) tile area
    for (int e = tid; e < NT*K3; e += 1024)
        tile[e] = tgt_kp[(size_t)bt0*K3 + e];
    __syncthreads();

    // per-lane target row -> registers (every wave redundantly; lanes 0..49)
    float dk[K3];
    float tl0=0,tl1=0,tl2=0,tr0=0,tr1=0,tr2=0,tvol=0;
    if (ln < NT) {
        const float* tb6 = tgt_boxes + (size_t)(bt0+ln)*6;
        float c0=tb6[0],c1=tb6[1],c2=tb6[2],s0=tb6[3],s1=tb6[4],s2=tb6[5];
        tl0=c0-0.5f*s0; tl1=c1-0.5f*s1; tl2=c2-0.5f*s2;
        tr0=c0+0.5f*s0; tr1=c1+0.5f*s1; tr2=c2+0.5f*s2;
        tvol=(tr0-tl0)*(tr1-tl1)*(tr2-tl2);
        #pragma unroll
        for (int c = 0; c < K3; ++c) {
            int d = c % 3;
            float L = (d==0)?tl0:((d==1)?tl1:tl2);
            float S = (d==0)?s0:((d==1)?s1:s2);
            dk[c] = (tile[ln*K3 + c] - L) / S;
        }
    }
    __syncthreads();

    // build cost tile: wave w handles preds p = w, w+16, ... (bitwise same math as C path)
    for (int p = w; p < NQ; p += 16) {
        const float* prow = pred_kp + (size_t)(bq0+p)*K3;
        const float* pb6  = pred_boxes + (size_t)(bq0+p)*6;
        float pc0=pb6[0],pc1=pb6[1],pc2=pb6[2],ps0=pb6[3],ps1=pb6[4],ps2=pb6[5];
        float plt0=pc0-0.5f*ps0, plt1=pc1-0.5f*ps1, plt2=pc2-0.5f*ps2;
        float prb0=pc0+0.5f*ps0, prb1=pc1+0.5f*ps1, prb2=pc2+0.5f*ps2;
        float pvol=(prb0-plt0)*(prb1-plt1)*(prb2-plt2);
        if (ln < NT) {
            float sum = 0.f;
            #pragma unroll
            for (int c = 0; c < K3; ++c) sum += fabsf(prow[c] - dk[c]);
            float g_ = giou_cost(plt0,plt1,plt2,prb0,prb1,prb2,pvol,
                                 tl0,tl1,tl2,tr0,tr1,tr2,tvol);
            tile[ln*TSTRIDE + p] = sum - g_;
        }
    }
    __syncthreads();

    // ---- per-row argmin scan for greedy JV init (all 16 waves in parallel) ----
    // Placed beyond the Dijkstra's max speculative read index (49*301+319 = 15068).
    float* s_rmv = smem + 15072;          // 50 floats: row min value
    int*   s_rmc = (int*)(smem + 15136);  // 50 ints:   row argmin column
    for (int r = w; r < NT; r += 16) {
        float bv = __builtin_inff(); int bj = 0x7fffffff;
        #pragma unroll
        for (int s = 0; s < 5; ++s) {
            int j = ln + 64*s;
            if (j < NQ) {
                float cv = tile[r*TSTRIDE + j];
                if (cv < bv || (cv == bv && j < bj)) { bv = cv; bj = j; }
            }
        }
        #pragma unroll
        for (int off = 32; off > 0; off >>= 1) {
            float ov = __shfl_xor(bv, off);
            int   oj = __shfl_xor(bj, off);
            if (ov < bv || (ov == bv && oj < bj)) { bv = ov; bj = oj; }
        }
        if (ln == 0) { s_rmv[r] = bv; s_rmc[r] = bj; }
    }
    __syncthreads();
    if (w != 0) return;                 // wave 0 continues alone; no more s_barrier

    // ---- register-resident JV shortest-augmenting-path (float64 duals) ----
    // Greedy init: u[i] = min_j c[i][j], v = 0 (feasible dual, tight at row argmin);
    // assign each row its argmin column first-row-wins. Only contested rows need
    // Dijkstra, and they start from already-tight duals. Exact optimal matching
    // (a.s. unique for continuous costs) => identical indices to the reference.
    // lane ln owns columns j = ln + 64*s (s=0..4); slot 4 invalid for ln>=44
    double u = 0.0;                     // dual for row ln (ln<50)
    int c4r = -1;                       // col4row[ln]
    if (ln < NT) u = (double)s_rmv[ln];
    int wantj = (ln < NT) ? s_rmc[ln] : -1;
    for (int r = 0; r < NT; ++r) {
        int j = __builtin_amdgcn_readlane(wantj, r);
        unsigned long long taken = __ballot((ln < NT) && (c4r == j));
        if (taken == 0ull && ln == r) c4r = j;
    }

    double v[5], sh[5];
    int pth[5];
    #pragma unroll
    for (int s = 0; s < 5; ++s) v[s] = 0.0;
    const double DINF = __builtin_inf();

    for (int curRow = 0; curRow < NT; ++curRow) {
        if (__builtin_amdgcn_readlane(c4r, curRow) >= 0) continue;  // greedy-assigned
        #pragma unroll
        for (int s = 0; s < 5; ++s) { sh[s] = DINF; pth[s] = -1; }
        int SCm = (ln < 44) ? 0 : 0x10;            // invalid slot pre-closed
        unsigned long long SRmask = 0ull;
        int i = curRow;
        double minVal = 0.0;
        int sink = -1;

        while (true) {
            SRmask |= (1ull << i);
            float cf[5];
            #pragma unroll
            for (int s = 0; s < 5; ++s) cf[s] = tile[i*TSTRIDE + ln + 64*s];
            double u_i = readlane_f64(u, i);       // i is wave-uniform -> v_readlane
            double lmin = DINF;
            #pragma unroll
            for (int s = 0; s < 5; ++s) {
                bool open = ((SCm >> s) & 1) == 0;
                double r = ((minVal + (double)cf[s]) - u_i) - v[s];  // reference op order
                bool upd = open && (r < sh[s]);
                sh[s]  = upd ? r : sh[s];
                pth[s] = upd ? i : pth[s];
                lmin = fmin(lmin, open ? sh[s] : DINF);
            }
            // exact f64 min over open columns
            double m = wave_min_f64(lmin);
            minVal = m;
            // argmin-j: first open column (ascending j = ln+64s) whose sh equals m.
            // j ordering is s-major then lane, so scan s ascending, ctz per ballot.
            unsigned long long b0 = __ballot((((SCm >> 0) & 1) == 0) && (sh[0] == m));
            unsigned long long b1 = __ballot((((SCm >> 1) & 1) == 0) && (sh[1] == m));
            unsigned long long b2 = __ballot((((SCm >> 2) & 1) == 0) && (sh[2] == m));
            unsigned long long b3 = __ballot((((SCm >> 3) & 1) == 0) && (sh[3] == m));
            unsigned long long b4 = __ballot((((SCm >> 4) & 1) == 0) && (sh[4] == m));
            int jstar;
            if      (b0) jstar =       __builtin_ctzll(b0);
            else if (b1) jstar =  64 + __builtin_ctzll(b1);
            else if (b2) jstar = 128 + __builtin_ctzll(b2);
            else if (b3) jstar = 192 + __builtin_ctzll(b3);
            else         jstar = 256 + __builtin_ctzll(b4);
            // close column jstar
            if (ln == (jstar & 63)) SCm |= 1 << (jstar >> 6);
            // row4col[jstar] via col4row ballot (col4row constant during Dijkstra)
            unsigned long long mm = __ballot((ln < NT) && (c4r == jstar));
            if (mm == 0ull) { sink = jstar; break; }
            i = __builtin_ctzll(mm);
        }

        // ---- dual updates (pre-augment col4row) ----
        int cg  = (c4r >= 0) ? c4r : 0;
        int gow = cg & 63, gsl = cg >> 6;
        double g0 = __shfl(sh[0], gow);
        double g1 = __shfl(sh[1], gow);
        double g2 = __shfl(sh[2], gow);
        double g3 = __shfl(sh[3], gow);
        double g4 = __shfl(sh[4], gow);
        double gg = g0;
        gg = (gsl == 1) ? g1 : gg;
        gg = (gsl == 2) ? g2 : gg;
        gg = (gsl == 3) ? g3 : gg;
        gg = (gsl == 4) ? g4 : gg;
        bool inSR = (ln < NT) && ((SRmask >> ln) & 1ull);
        double du = (ln == curRow) ? minVal : (minVal - gg);
        u = inSR ? (u + du) : u;
        #pragma unroll
        for (int s = 0; s < 5; ++s) {
            bool closed = ((SCm >> s) & 1) != 0;
            v[s] = closed ? (v[s] - (minVal - sh[s])) : v[s];
        }

        // ---- augment (uniform j/i chain -> readlane) ----
        int j = sink;
        while (true) {
            int ow2 = j & 63, sl2 = j >> 6;
            int ps = pth[0];
            ps = (sl2==1) ? pth[1] : ps;
            ps = (sl2==2) ? pth[2] : ps;
            ps = (sl2==3) ? pth[3] : ps;
            ps = (sl2==4) ? pth[4] : ps;
            int ii = __builtin_amdgcn_readlane(ps, ow2);   // path[j]
            int jj = __builtin_amdgcn_readlane(c4r, ii);   // old col4row[ii]
            if (ln == ii) c4r = j;                          // col4row[ii] = j
            j = jj;
            if (ii == curRow) break;
        }
    }

    // ---- emit indices (argsort of matched pred indices) ----
    int* smem_i = (int*)smem;                       // tile is dead
    __threadfence_block();
    if (ln < NT) smem_i[ln] = c4r;
    __threadfence_block();
    int myc = c4r;
    int rank = 0;
    for (int s2 = 0; s2 < NT; ++s2) rank += (smem_i[s2] < myc) ? 1 : 0;
    if (ln < NT) {
        out_idx[b*(2*NT) + rank]      = (float)myc; // sorted pred (q) indices
        out_idx[b*(2*NT) + NT + rank] = (float)ln;  // matched tgt (t) indices
    }
}

extern "C" void kernel_launch(void* const* d_in, const int* in_sizes, int n_in,
                              void* d_out, int out_size, void* d_ws, size_t ws_size,
                              hipStream_t stream)
{
    const float* pred_kp    = (const float*)d_in[0];
    const float* pred_boxes = (const float*)d_in[1];
    const float* tgt_boxes  = (const float*)d_in[2];
    const float* tgt_kp     = (const float*)d_in[3];
    float* C   = (float*)d_out;
    float* idx = C + NC;
    // blocks 0..15: per-batch LAP (dispatched first); blocks 16..765: cost matrix
    fused_kernel<<<dim3(BSZ + 750), 1024, 0, stream>>>(
        pred_kp, pred_boxes, tgt_boxes, tgt_kp, C, idx);
}

// Round 3
// 129.472 us; speedup vs baseline: 1.1622x; 1.0067x over previous
//
#include <hip/hip_runtime.h>
#include <math.h>

#define BSZ 16
#define NQ 300
#define NT 50
#define K3 51
#define NPRED (BSZ*NQ)     // 4800
#define NTGT  (BSZ*NT)     // 800
#define NC    (NPRED*NTGT) // 3,840,000
#define TSTRIDE 301        // lap tile row stride (floats), odd -> conflict-free
#define SMEMF 15232        // floats: 50*301 tile + rowmin scratch (60.9 KB, 2 blk/CU)

// NOTE (R2 post-mortem): warm column duals v[j] = min_t(c-u) > 0 are INFEASIBLE for
// the rectangular LAP dual (requires v <= 0, and v < 0 only on finally-matched
// columns). Do NOT re-introduce nonzero v init; with v = 0 the row-argmin greedy
// claim below is already the maximum tight initial matching.

// ---------------- DPP wave-min helper (wave64, all lanes active) ----------------
template<int CTRL, int RMASK>
__device__ __forceinline__ double dpp_minstep_f64(double x) {
    long long bb = __double_as_longlong(x);
    int lo = (int)(bb & 0xFFFFFFFFll);
    int hi = (int)(bb >> 32);
    int mlo = __builtin_amdgcn_update_dpp(lo, lo, CTRL, RMASK, 0xF, false);
    int mhi = __builtin_amdgcn_update_dpp(hi, hi, CTRL, RMASK, 0xF, false);
    double other = __longlong_as_double(((long long)mhi << 32) | (long long)(unsigned)mlo);
    return fmin(x, other);
}
__device__ __forceinline__ double wave_min_f64(double x) {
    x = dpp_minstep_f64<0xB1, 0xF>(x);
    x = dpp_minstep_f64<0x4E, 0xF>(x);
    x = dpp_minstep_f64<0x141, 0xF>(x);
    x = dpp_minstep_f64<0x140, 0xF>(x);
    x = dpp_minstep_f64<0x142, 0xA>(x);   // lanes 16-31,48-63 <- lane 15/47
    x = dpp_minstep_f64<0x143, 0xC>(x);   // lanes 32-63 <- lane 31; lane 63 = global min
    long long bb = __double_as_longlong(x);
    int lo = __builtin_amdgcn_readlane((int)(bb & 0xFFFFFFFFll), 63);
    int hi = __builtin_amdgcn_readlane((int)(bb >> 32), 63);
    return __longlong_as_double(((long long)hi << 32) | (long long)(unsigned)lo);
}
__device__ __forceinline__ double readlane_f64(double x, int lane) {
    long long bb = __double_as_longlong(x);
    int lo = __builtin_amdgcn_readlane((int)(bb & 0xFFFFFFFFll), lane);
    int hi = __builtin_amdgcn_readlane((int)(bb >> 32), lane);
    return __longlong_as_double(((long long)hi << 32) | (long long)(unsigned)lo);
}

// Identical formula/op-order used by BOTH paths -> bitwise-identical cost values.
__device__ __forceinline__ float giou_cost(
    float plt0, float plt1, float plt2, float prb0, float prb1, float prb2, float pvol,
    float tlt0, float tlt1, float tlt2, float trb0, float trb1, float trb2, float tvol)
{
    float inter = fmaxf(fminf(prb0,trb0) - fmaxf(plt0,tlt0), 0.f);
    inter *= fmaxf(fminf(prb1,trb1) - fmaxf(plt1,tlt1), 0.f);
    inter *= fmaxf(fminf(prb2,trb2) - fmaxf(plt2,tlt2), 0.f);
    float evol = fmaxf(fmaxf(prb0,trb0) - fminf(plt0,tlt0), 0.f);
    evol *= fmaxf(fmaxf(prb1,trb1) - fminf(plt1,tlt1), 0.f);
    evol *= fmaxf(fmaxf(prb2,trb2) - fminf(plt2,tlt2), 0.f);
    float uni = pvol + tvol - inter;
    return inter/uni - (evol - uni)/evol;
}

__global__ __launch_bounds__(1024) void fused_kernel(
    const float* __restrict__ pred_kp, const float* __restrict__ pred_boxes,
    const float* __restrict__ tgt_boxes, const float* __restrict__ tgt_kp,
    float* __restrict__ C, float* __restrict__ out_idx)
{
    __shared__ __align__(16) float smem[SMEMF];
    const int bid = blockIdx.x;
    const int tid = threadIdx.x;

    if (bid >= BSZ) {
        // ================= cost-matrix path: 64 preds x 80 tgts per block =================
        const int cb = bid - BSZ;
        const int pb = cb % 75, tb = cb / 75;
        const int p0 = pb * 64, t0 = tb * 80;
        float* s_dk   = smem;            // 80 x 56 (padded, 16B-aligned rows)
        float* s_tbox = smem + 4480;     // 80 x 12: lt0-2, rb0-2, vol, pad, pad, s0-2
        float* s_pk   = smem + 5440;     // 64 x 51

        if (tid < 80) {
            const float* tb6 = tgt_boxes + (size_t)(t0 + tid) * 6;
            float c0=tb6[0], c1=tb6[1], c2=tb6[2], s0=tb6[3], s1=tb6[4], s2=tb6[5];
            float l0=c0-0.5f*s0, l1=c1-0.5f*s1, l2=c2-0.5f*s2;
            float r0=c0+0.5f*s0, r1=c1+0.5f*s1, r2=c2+0.5f*s2;
            float* tw = s_tbox + tid*12;
            tw[0]=l0; tw[1]=l1; tw[2]=l2; tw[3]=r0; tw[4]=r1; tw[5]=r2;
            tw[6]=(r0-l0)*(r1-l1)*(r2-l2);
            tw[9]=s0; tw[10]=s1; tw[11]=s2;
        }
        __syncthreads();
        for (int e = tid; e < 80*K3; e += 1024) {
            int t = e / K3; int c = e - t*K3; int d = c % 3;
            float kp = tgt_kp[(size_t)t0*K3 + e];
            s_dk[t*56 + c] = (kp - s_tbox[t*12 + d]) / s_tbox[t*12 + 9 + d];
        }
        for (int e = tid; e < 64*K3; e += 1024)
            s_pk[e] = pred_kp[(size_t)p0*K3 + e];
        __syncthreads();

        const int pl = tid & 63, g = tid >> 6;
        float a[K3];
        #pragma unroll
        for (int c = 0; c < K3; ++c) a[c] = s_pk[pl*K3 + c];
        const int p = p0 + pl;
        const float* pb6 = pred_boxes + (size_t)p * 6;
        float pc0=pb6[0],pc1=pb6[1],pc2=pb6[2],ps0=pb6[3],ps1=pb6[4],ps2=pb6[5];
        float plt0=pc0-0.5f*ps0, plt1=pc1-0.5f*ps1, plt2=pc2-0.5f*ps2;
        float prb0=pc0+0.5f*ps0, prb1=pc1+0.5f*ps1, prb2=pc2+0.5f*ps2;
        float pvol=(prb0-plt0)*(prb1-plt1)*(prb2-plt2);

        #pragma unroll
        for (int k = 0; k < 5; ++k) {
            int tl = g*5 + k;                       // wave-uniform -> broadcast LDS reads
            const float* bbp = s_dk + tl*56;
            float sum = 0.f;
            #pragma unroll
            for (int c4 = 0; c4 < 12; ++c4) {       // ascending c, serial adds (order fixed)
                float4 q = *(const float4*)(bbp + 4*c4);
                sum += fabsf(a[4*c4+0] - q.x);
                sum += fabsf(a[4*c4+1] - q.y);
                sum += fabsf(a[4*c4+2] - q.z);
                sum += fabsf(a[4*c4+3] - q.w);
            }
            sum += fabsf(a[48] - bbp[48]);
            sum += fabsf(a[49] - bbp[49]);
            sum += fabsf(a[50] - bbp[50]);
            const float* tw = s_tbox + tl*12;
            float g_ = giou_cost(plt0,plt1,plt2,prb0,prb1,prb2,pvol,
                                 tw[0],tw[1],tw[2],tw[3],tw[4],tw[5],tw[6]);
            C[(size_t)p*NTGT + (t0+tl)] = sum - g_;
        }
        return;
    }

    // ================= LAP path: one block per batch =================
    const int b = bid;
    const int ln = tid & 63, w = tid >> 6;
    const int bq0 = b*NQ, bt0 = b*NT;
    float* tile = smem;                 // becomes [50][301] cost tile

    // stage tgt_kp slice into (future) tile area
    for (int e = tid; e < NT*K3; e += 1024)
        tile[e] = tgt_kp[(size_t)bt0*K3 + e];
    __syncthreads();

    // per-lane target row -> registers (every wave redundantly; lanes 0..49)
    float dk[K3];
    float tl0=0,tl1=0,tl2=0,tr0=0,tr1=0,tr2=0,tvol=0;
    if (ln < NT) {
        const float* tb6 = tgt_boxes + (size_t)(bt0+ln)*6;
        float c0=tb6[0],c1=tb6[1],c2=tb6[2],s0=tb6[3],s1=tb6[4],s2=tb6[5];
        tl0=c0-0.5f*s0; tl1=c1-0.5f*s1; tl2=c2-0.5f*s2;
        tr0=c0+0.5f*s0; tr1=c1+0.5f*s1; tr2=c2+0.5f*s2;
        tvol=(tr0-tl0)*(tr1-tl1)*(tr2-tl2);
        #pragma unroll
        for (int c = 0; c < K3; ++c) {
            int d = c % 3;
            float L = (d==0)?tl0:((d==1)?tl1:tl2);
            float S = (d==0)?s0:((d==1)?s1:s2);
            dk[c] = (tile[ln*K3 + c] - L) / S;
        }
    }
    __syncthreads();

    // build cost tile: wave w handles preds p = w, w+16, ... (bitwise same math as C path)
    for (int p = w; p < NQ; p += 16) {
        const float* prow = pred_kp + (size_t)(bq0+p)*K3;
        const float* pb6  = pred_boxes + (size_t)(bq0+p)*6;
        float pc0=pb6[0],pc1=pb6[1],pc2=pb6[2],ps0=pb6[3],ps1=pb6[4],ps2=pb6[5];
        float plt0=pc0-0.5f*ps0, plt1=pc1-0.5f*ps1, plt2=pc2-0.5f*ps2;
        float prb0=pc0+0.5f*ps0, prb1=pc1+0.5f*ps1, prb2=pc2+0.5f*ps2;
        float pvol=(prb0-plt0)*(prb1-plt1)*(prb2-plt2);
        if (ln < NT) {
            float sum = 0.f;
            #pragma unroll
            for (int c = 0; c < K3; ++c) sum += fabsf(prow[c] - dk[c]);
            float g_ = giou_cost(plt0,plt1,plt2,prb0,prb1,prb2,pvol,
                                 tl0,tl1,tl2,tr0,tr1,tr2,tvol);
            tile[ln*TSTRIDE + p] = sum - g_;
        }
    }
    __syncthreads();

    // ---- per-row argmin scan for greedy JV init (all 16 waves in parallel) ----
    // Placed beyond the Dijkstra's max speculative read index (49*301+319 = 15068).
    float* s_rmv = smem + 15072;          // 50 floats: row min value
    int*   s_rmc = (int*)(smem + 15136);  // 50 ints:   row argmin column
    for (int r = w; r < NT; r += 16) {
        float bv = __builtin_inff(); int bj = 0x7fffffff;
        #pragma unroll
        for (int s = 0; s < 5; ++s) {
            int j = ln + 64*s;
            if (j < NQ) {
                float cv = tile[r*TSTRIDE + j];
                if (cv < bv || (cv == bv && j < bj)) { bv = cv; bj = j; }
            }
        }
        #pragma unroll
        for (int off = 32; off > 0; off >>= 1) {
            float ov = __shfl_xor(bv, off);
            int   oj = __shfl_xor(bj, off);
            if (ov < bv || (ov == bv && oj < bj)) { bv = ov; bj = oj; }
        }
        if (ln == 0) { s_rmv[r] = bv; s_rmc[r] = bj; }
    }
    __syncthreads();
    if (w != 0) return;                 // wave 0 continues alone; no more s_barrier

    // ---- register-resident JV shortest-augmenting-path (float64 duals) ----
    // Greedy init: u[i] = min_j c[i][j], v = 0 (feasible dual, tight at row argmin);
    // assign each row its argmin column first-row-wins. Only contested rows need
    // Dijkstra, and they start from already-tight duals. Exact optimal matching
    // (a.s. unique for continuous costs) => identical indices to the reference.
    // lane ln owns columns j = ln + 64*s (s=0..4); slot 4 invalid for ln>=44
    double u = 0.0;                     // dual for row ln (ln<50)
    int c4r = -1;                       // col4row[ln]
    if (ln < NT) u = (double)s_rmv[ln];
    int wantj = (ln < NT) ? s_rmc[ln] : -1;
    for (int r = 0; r < NT; ++r) {
        int j = __builtin_amdgcn_readlane(wantj, r);
        unsigned long long taken = __ballot((ln < NT) && (c4r == j));
        if (taken == 0ull && ln == r) c4r = j;
    }

    double v[5], sh[5];
    int pth[5];
    #pragma unroll
    for (int s = 0; s < 5; ++s) v[s] = 0.0;
    const double DINF = __builtin_inf();

    for (int curRow = 0; curRow < NT; ++curRow) {
        if (__builtin_amdgcn_readlane(c4r, curRow) >= 0) continue;  // greedy-assigned
        #pragma unroll
        for (int s = 0; s < 5; ++s) { sh[s] = DINF; pth[s] = -1; }
        int SCm = (ln < 44) ? 0 : 0x10;            // invalid slot pre-closed
        unsigned long long SRmask = 0ull;
        int i = curRow;
        double minVal = 0.0;
        int sink = -1;

        while (true) {
            SRmask |= (1ull << i);
            float cf[5];
            #pragma unroll
            for (int s = 0; s < 5; ++s) cf[s] = tile[i*TSTRIDE + ln + 64*s];
            double u_i = readlane_f64(u, i);       // i is wave-uniform -> v_readlane
            double e[5];
            #pragma unroll
            for (int s = 0; s < 5; ++s) {
                bool open = ((SCm >> s) & 1) == 0;
                double r = ((minVal + (double)cf[s]) - u_i) - v[s];  // reference op order
                bool upd = open && (r < sh[s]);
                sh[s]  = upd ? r : sh[s];
                pth[s] = upd ? i : pth[s];
                e[s] = open ? sh[s] : DINF;
            }
            // depth-3 fmin tree (exact: fmin assoc/comm over NaN-free values incl inf)
            double lmin = fmin(fmin(fmin(e[0], e[1]), fmin(e[2], e[3])), e[4]);
            // exact f64 min over open columns
            double m = wave_min_f64(lmin);
            minVal = m;
            // argmin-j: first open column (ascending j = ln+64s) whose sh equals m.
            // j ordering is s-major then lane, so scan s ascending, ctz per ballot.
            unsigned long long b0 = __ballot((((SCm >> 0) & 1) == 0) && (sh[0] == m));
            unsigned long long b1 = __ballot((((SCm >> 1) & 1) == 0) && (sh[1] == m));
            unsigned long long b2 = __ballot((((SCm >> 2) & 1) == 0) && (sh[2] == m));
            unsigned long long b3 = __ballot((((SCm >> 3) & 1) == 0) && (sh[3] == m));
            unsigned long long b4 = __ballot((((SCm >> 4) & 1) == 0) && (sh[4] == m));
            int jstar;
            if      (b0) jstar =       __builtin_ctzll(b0);
            else if (b1) jstar =  64 + __builtin_ctzll(b1);
            else if (b2) jstar = 128 + __builtin_ctzll(b2);
            else if (b3) jstar = 192 + __builtin_ctzll(b3);
            else         jstar = 256 + __builtin_ctzll(b4);
            // row4col[jstar] via col4row ballot (col4row constant during Dijkstra)
            unsigned long long mm = __ballot((ln < NT) && (c4r == jstar));
            // close column jstar
            if (ln == (jstar & 63)) SCm |= 1 << (jstar >> 6);
            if (mm == 0ull) { sink = jstar; break; }
            i = __builtin_ctzll(mm);
        }

        // ---- dual updates (pre-augment col4row) ----
        int cg  = (c4r >= 0) ? c4r : 0;
        int gow = cg & 63, gsl = cg >> 6;
        double g0 = __shfl(sh[0], gow);
        double g1 = __shfl(sh[1], gow);
        double g2 = __shfl(sh[2], gow);
        double g3 = __shfl(sh[3], gow);
        double g4 = __shfl(sh[4], gow);
        double gg = g0;
        gg = (gsl == 1) ? g1 : gg;
        gg = (gsl == 2) ? g2 : gg;
        gg = (gsl == 3) ? g3 : gg;
        gg = (gsl == 4) ? g4 : gg;
        bool inSR = (ln < NT) && ((SRmask >> ln) & 1ull);
        double du = (ln == curRow) ? minVal : (minVal - gg);
        u = inSR ? (u + du) : u;
        #pragma unroll
        for (int s = 0; s < 5; ++s) {
            bool closed = ((SCm >> s) & 1) != 0;
            v[s] = closed ? (v[s] - (minVal - sh[s])) : v[s];
        }

        // ---- augment (uniform j/i chain -> readlane) ----
        int j = sink;
        while (true) {
            int ow2 = j & 63, sl2 = j >> 6;
            int ps = pth[0];
            ps = (sl2==1) ? pth[1] : ps;
            ps = (sl2==2) ? pth[2] : ps;
            ps = (sl2==3) ? pth[3] : ps;
            ps = (sl2==4) ? pth[4] : ps;
            int ii = __builtin_amdgcn_readlane(ps, ow2);   // path[j]
            int jj = __builtin_amdgcn_readlane(c4r, ii);   // old col4row[ii]
            if (ln == ii) c4r = j;                          // col4row[ii] = j
            j = jj;
            if (ii == curRow) break;
        }
    }

    // ---- emit indices (argsort of matched pred indices) ----
    int* smem_i = (int*)smem;                       // tile is dead
    __threadfence_block();
    if (ln < NT) smem_i[ln] = c4r;
    __threadfence_block();
    int myc = c4r;
    int rank = 0;
    for (int s2 = 0; s2 < NT; ++s2) rank += (smem_i[s2] < myc) ? 1 : 0;
    if (ln < NT) {
        out_idx[b*(2*NT) + rank]      = (float)myc; // sorted pred (q) indices
        out_idx[b*(2*NT) + NT + rank] = (float)ln;  // matched tgt (t) indices
    }
}

extern "C" void kernel_launch(void* const* d_in, const int* in_sizes, int n_in,
                              void* d_out, int out_size, void* d_ws, size_t ws_size,
                              hipStream_t stream)
{
    const float* pred_kp    = (const float*)d_in[0];
    const float* pred_boxes = (const float*)d_in[1];
    const float* tgt_boxes  = (const float*)d_in[2];
    const float* tgt_kp     = (const float*)d_in[3];
    float* C   = (float*)d_out;
    float* idx = C + NC;
    // blocks 0..15: per-batch LAP (dispatched first); blocks 16..765: cost matrix
    fused_kernel<<<dim3(BSZ + 750), 1024, 0, stream>>>(
        pred_kp, pred_boxes, tgt_boxes, tgt_kp, C, idx);
}